// Round 1
// baseline (2241.893 us; speedup 1.0000x reference)
//
#include <hip/hip_runtime.h>
#include <hip/hip_bf16.h>

// Problem constants
#define Bb 4
#define Tt 4096
#define Dd 2048
#define Mm (Bb*Tt)          // 16384 rows
#define TILE 128
#define BK 32
#define LDSS 40             // LDS row stride in shorts (32 + 8 pad -> 2-way bank alias = free)
#define CHUNK 64            // scan chunk length
#define NCHUNK (Tt/CHUNK)   // 64 chunks

typedef short  short8  __attribute__((ext_vector_type(8)));
typedef float  floatx4 __attribute__((ext_vector_type(4)));

static __device__ __forceinline__ short f2bf(float f) {
    union { float f; unsigned u; } x; x.f = f;
    unsigned r = x.u + 0x7fffu + ((x.u >> 16) & 1u);   // RNE
    return (short)(r >> 16);
}
static __device__ __forceinline__ float mixf(float xv, float sv, float tv) {
    return fmaf(tv, xv - sv, sv);    // x*t + s*(1-t)
}
static __device__ __forceinline__ float siluf(float v) {
    return v / (1.f + __expf(-v));
}

// One GEMM kernel, three A-operand modes:
//   MODE 0: A[m][k] = mix(x[m][k], x[m-1][k] (time-shift), tm[k])           (K,V proj)
//   MODE 1: A = silu(mix(...))                                              (R proj)
//   MODE 2: A = precomputed bf16 matrix (wkv*r)                             (out proj)
// C[m][n] = sum_k A[m][k]*W[n][k] + bias[n], fp32 out. M=16384, N=K=2048.
template<int MODE>
__global__ __launch_bounds__(256)
void gemm_k(const float* __restrict__ X, const short* __restrict__ Abf,
            const float* __restrict__ tm, const float* __restrict__ W,
            const float* __restrict__ bias, float* __restrict__ Cout)
{
    __shared__ short As[TILE*LDSS];
    __shared__ short Bs[TILE*LDSS];

    const int tid  = threadIdx.x;
    const int lane = tid & 63, wave = tid >> 6;
    const int row0 = blockIdx.x * TILE;
    const int col0 = blockIdx.y * TILE;

    // staging assignment: thread -> (row sr, 16-elem k-half sh)
    const int sr = tid >> 1;
    const int sh = (tid & 1) * 16;
    const int gr = row0 + sr;

    const float* xrow = nullptr; const float* xsrow = nullptr; int tpos = 1;
    if constexpr (MODE != 2) {
        tpos  = gr & (Tt - 1);                 // position within batch; 0 -> shifted row is zeros
        xrow  = X + (size_t)gr * Dd;
        xsrow = xrow - Dd;
    }
    const float* wrow = W + (size_t)(col0 + sr) * Dd;

    const int wm = (wave >> 1) * 64, wn = (wave & 1) * 64;
    const int fm = lane & 15, fq = lane >> 4;

    floatx4 acc[4][4];
    #pragma unroll
    for (int i = 0; i < 4; i++)
        #pragma unroll
        for (int j = 0; j < 4; j++) acc[i][j] = (floatx4){0.f,0.f,0.f,0.f};

    for (int k0 = 0; k0 < Dd; k0 += BK) {
        short8 av[2], bv[2];
        // ---- A staging to regs ----
        if constexpr (MODE == 2) {
            const short* ap = Abf + (size_t)gr * Dd + k0 + sh;
            av[0] = *(const short8*)(ap);
            av[1] = *(const short8*)(ap + 8);
        } else {
            #pragma unroll
            for (int h = 0; h < 2; ++h) {
                #pragma unroll
                for (int q = 0; q < 2; ++q) {
                    const int off = k0 + sh + h*8 + q*4;
                    float4 xv = *(const float4*)(xrow + off);
                    float4 tv = *(const float4*)(tm + off);
                    float4 sv = make_float4(0.f,0.f,0.f,0.f);
                    if (tpos > 0) sv = *(const float4*)(xsrow + off);
                    float m0 = mixf(xv.x, sv.x, tv.x);
                    float m1 = mixf(xv.y, sv.y, tv.y);
                    float m2 = mixf(xv.z, sv.z, tv.z);
                    float m3 = mixf(xv.w, sv.w, tv.w);
                    if constexpr (MODE == 1) {
                        m0 = siluf(m0); m1 = siluf(m1); m2 = siluf(m2); m3 = siluf(m3);
                    }
                    av[h][q*4+0] = f2bf(m0);
                    av[h][q*4+1] = f2bf(m1);
                    av[h][q*4+2] = f2bf(m2);
                    av[h][q*4+3] = f2bf(m3);
                }
            }
        }
        // ---- B staging to regs (W fp32 -> bf16) ----
        #pragma unroll
        for (int h = 0; h < 2; ++h) {
            #pragma unroll
            for (int q = 0; q < 2; ++q) {
                const int off = k0 + sh + h*8 + q*4;
                float4 wv = *(const float4*)(wrow + off);
                bv[h][q*4+0] = f2bf(wv.x);
                bv[h][q*4+1] = f2bf(wv.y);
                bv[h][q*4+2] = f2bf(wv.z);
                bv[h][q*4+3] = f2bf(wv.w);
            }
        }

        __syncthreads();   // previous iteration's LDS reads complete
        *(short8*)(As + sr*LDSS + sh    ) = av[0];
        *(short8*)(As + sr*LDSS + sh + 8) = av[1];
        *(short8*)(Bs + sr*LDSS + sh    ) = bv[0];
        *(short8*)(Bs + sr*LDSS + sh + 8) = bv[1];
        __syncthreads();

        // ---- fragments + MFMA ----
        short8 af[4], bfr[4];
        #pragma unroll
        for (int i = 0; i < 4; i++)
            af[i] = *(const short8*)(As + (wm + i*16 + fm)*LDSS + fq*8);
        #pragma unroll
        for (int j = 0; j < 4; j++)
            bfr[j] = *(const short8*)(Bs + (wn + j*16 + fm)*LDSS + fq*8);
        #pragma unroll
        for (int i = 0; i < 4; i++)
            #pragma unroll
            for (int j = 0; j < 4; j++)
                acc[i][j] = __builtin_amdgcn_mfma_f32_16x16x32_bf16(af[i], bfr[j], acc[i][j], 0, 0, 0);
    }

    // ---- epilogue: C/D layout col=lane&15, row=(lane>>4)*4+r ----
    #pragma unroll
    for (int j = 0; j < 4; j++) {
        const int gc = col0 + wn + j*16 + fm;
        const float bj = bias[gc];
        #pragma unroll
        for (int i = 0; i < 4; i++) {
            const int grow = row0 + wm + i*16 + fq*4;
            float* cp = Cout + (size_t)grow * Dd + gc;
            #pragma unroll
            for (int r = 0; r < 4; r++)
                cp[(size_t)r * Dd] = acc[i][j][r] + bj;
        }
    }
}

// ---------------- chunked WKV scan ----------------
// recurrence: t=max(u+k,w); e1=exp(-w-t); e2=exp(u+k-t); a=e1*a+e2*v; b=e1*b+e2; out=a/b
// affine in (a,b) -> chunk it: pass1 per-chunk (A,B,decay) from zero init,
// pass2 tiny sequential combine over chunks, pass3 replay with true init.

__global__ __launch_bounds__(256)
void scan1(const float* __restrict__ K, const float* __restrict__ V,
           const float* __restrict__ u, const float* __restrict__ w,
           float* __restrict__ Asum, float* __restrict__ Bsum, float* __restrict__ Dsum)
{
    const int c = blockIdx.x, b = blockIdx.y;
    const int d = blockIdx.z * 256 + threadIdx.x;
    const float uu = u[d], ww = w[d];
    const size_t base = ((size_t)(b*Tt + c*CHUNK)) * Dd + d;
    float a = 0.f, bb = 0.f, dd = 1.f;
    #pragma unroll 4
    for (int t = 0; t < CHUNK; t++) {
        const float k = K[base + (size_t)t*Dd];
        const float v = V[base + (size_t)t*Dd];
        const float tt = fmaxf(uu + k, ww);
        const float e1 = __expf(-ww - tt);
        const float e2 = __expf(uu + k - tt);
        a  = e1*a  + e2*v;
        bb = e1*bb + e2;
        dd *= e1;
    }
    const size_t idx = ((size_t)c*Bb + b) * Dd + d;
    Asum[idx] = a; Bsum[idx] = bb; Dsum[idx] = dd;
}

__global__ __launch_bounds__(256)
void scan2(const float* __restrict__ Asum, const float* __restrict__ Bsum,
           const float* __restrict__ Dsum, float* __restrict__ Sa, float* __restrict__ Sb)
{
    const int g = blockIdx.x * 256 + threadIdx.x;   // channel over (b,d): 0..8191
    float a = 0.f, bb = 0.f;
    for (int c = 0; c < NCHUNK; c++) {
        const size_t idx = (size_t)c * (Bb*Dd) + g;
        Sa[idx] = a; Sb[idx] = bb;
        const float dd = Dsum[idx];
        a  = dd*a  + Asum[idx];
        bb = dd*bb + Bsum[idx];
    }
}

__global__ __launch_bounds__(256)
void scan3(const float* __restrict__ K, const float* __restrict__ V,
           const float* __restrict__ R,
           const float* __restrict__ Sa, const float* __restrict__ Sb,
           const float* __restrict__ u, const float* __restrict__ w,
           short* __restrict__ AF)
{
    const int c = blockIdx.x, b = blockIdx.y;
    const int d = blockIdx.z * 256 + threadIdx.x;
    const float uu = u[d], ww = w[d];
    const size_t sidx = ((size_t)c*Bb + b) * Dd + d;
    float a = Sa[sidx], bb = Sb[sidx];
    const size_t base = ((size_t)(b*Tt + c*CHUNK)) * Dd + d;
    #pragma unroll 4
    for (int t = 0; t < CHUNK; t++) {
        const float k = K[base + (size_t)t*Dd];
        const float v = V[base + (size_t)t*Dd];
        const float tt = fmaxf(uu + k, ww);
        const float e1 = __expf(-ww - tt);
        const float e2 = __expf(uu + k - tt);
        a  = e1*a  + e2*v;
        bb = e1*bb + e2;
        const float wkv = a / bb;
        const float r = R[base + (size_t)t*Dd];
        AF[base + (size_t)t*Dd] = f2bf(wkv * r);
    }
}

extern "C" void kernel_launch(void* const* d_in, const int* in_sizes, int n_in,
                              void* d_out, int out_size, void* d_ws, size_t ws_size,
                              hipStream_t stream)
{
    const float* x   = (const float*)d_in[0];
    const float* Wk  = (const float*)d_in[1];
    const float* bk  = (const float*)d_in[2];
    const float* Wv  = (const float*)d_in[3];
    const float* bv  = (const float*)d_in[4];
    const float* Wr  = (const float*)d_in[5];
    const float* br  = (const float*)d_in[6];
    const float* Wo  = (const float*)d_in[7];
    const float* bo  = (const float*)d_in[8];
    const float* tmk = (const float*)d_in[9];
    const float* tmv = (const float*)d_in[10];
    const float* tmr = (const float*)d_in[11];
    const float* u   = (const float*)d_in[12];
    const float* w   = (const float*)d_in[13];

    char* ws = (char*)d_ws;
    float* Kb   = (float*)(ws);                         // 128 MB  (M x D fp32)
    float* Vb   = (float*)(ws + 0x08000000ull);         // 128 MB
    float* Rb   = (float*)(ws + 0x10000000ull);         // 128 MB
    short* AF   = (short*)(ws + 0x18000000ull);         //  64 MB  (M x D bf16)
    float* Asum = (float*)(ws + 0x1C000000ull);         //   2 MB  (NCHUNK x B x D)
    float* Bsum = (float*)(ws + 0x1C200000ull);
    float* Dsum = (float*)(ws + 0x1C400000ull);
    float* Sa   = (float*)(ws + 0x1C600000ull);
    float* Sb   = (float*)(ws + 0x1C800000ull);

    dim3 gg(Mm/TILE, Dd/TILE);   // 128 x 16 blocks
    gemm_k<0><<<gg, 256, 0, stream>>>(x, nullptr, tmk, Wk, bk, Kb);
    gemm_k<0><<<gg, 256, 0, stream>>>(x, nullptr, tmv, Wv, bv, Vb);
    gemm_k<1><<<gg, 256, 0, stream>>>(x, nullptr, tmr, Wr, br, Rb);

    scan1<<<dim3(NCHUNK, Bb, Dd/256), 256, 0, stream>>>(Kb, Vb, u, w, Asum, Bsum, Dsum);
    scan2<<<dim3((Bb*Dd)/256), 256, 0, stream>>>(Asum, Bsum, Dsum, Sa, Sb);
    scan3<<<dim3(NCHUNK, Bb, Dd/256), 256, 0, stream>>>(Kb, Vb, Rb, Sa, Sb, u, w, AF);

    gemm_k<2><<<gg, 256, 0, stream>>>(nullptr, AF, nullptr, Wo, bo, (float*)d_out);
}

// Round 2
// 1140.676 us; speedup vs baseline: 1.9654x; 1.9654x over previous
//
#include <hip/hip_runtime.h>
#include <hip/hip_bf16.h>

// Problem constants
#define Bb 4
#define Tt 4096
#define Dd 2048
#define Mm (Bb*Tt)          // 16384 rows; note M*N*K == 4096^3 exactly
#define CHUNK 64
#define NCHUNK (Tt/CHUNK)

typedef short  short8  __attribute__((ext_vector_type(8)));
typedef float  floatx4 __attribute__((ext_vector_type(4)));

static __device__ __forceinline__ short f2bf(float f) {
    union { float f; unsigned u; } x; x.f = f;
    unsigned r = x.u + 0x7fffu + ((x.u >> 16) & 1u);   // RNE
    return (short)(r >> 16);
}
static __device__ __forceinline__ float bf2f(short s) {
    union { unsigned u; float f; } x; x.u = ((unsigned)(unsigned short)s) << 16;
    return x.f;
}
static __device__ __forceinline__ float siluf(float v) { return v / (1.f + __expf(-v)); }
static __device__ __forceinline__ float mixf(float xv, float sv, float tv) {
    return fmaf(tv, xv - sv, sv);    // x*t + s*(1-t)
}

// async global->LDS, 16B per lane, dest = wave-uniform base + lane*16
#define GLDS16(gp, lp) __builtin_amdgcn_global_load_lds( \
    (const __attribute__((address_space(1))) void*)(gp), \
    (__attribute__((address_space(3))) void*)(lp), 16, 0, 0)

static __device__ __forceinline__ short8 pack8(float4 a, float4 b) {
    short8 r;
    r[0]=f2bf(a.x); r[1]=f2bf(a.y); r[2]=f2bf(a.z); r[3]=f2bf(a.w);
    r[4]=f2bf(b.x); r[5]=f2bf(b.y); r[6]=f2bf(b.z); r[7]=f2bf(b.w);
    return r;
}

// ---- prep: weights fp32 -> bf16 (once) ----
__global__ __launch_bounds__(256)
void prep_w(const float* __restrict__ w0, const float* __restrict__ w1,
            const float* __restrict__ w2, const float* __restrict__ w3,
            short* __restrict__ o0, short* __restrict__ o1,
            short* __restrict__ o2, short* __restrict__ o3)
{
    const float* s; short* d;
    switch (blockIdx.y) {
        case 0: s = w0; d = o0; break;
        case 1: s = w1; d = o1; break;
        case 2: s = w2; d = o2; break;
        default: s = w3; d = o3; break;
    }
    const size_t e = ((size_t)blockIdx.x * 256 + threadIdx.x) * 8;
    float4 a = *(const float4*)(s + e);
    float4 b = *(const float4*)(s + e + 4);
    *(short8*)(d + e) = pack8(a, b);
}

// ---- prep: A-operands (mix / silu(mix)) fp32 -> bf16 (once) ----
__global__ __launch_bounds__(256)
void prep_a(const float* __restrict__ x,
            const float* __restrict__ tmk, const float* __restrict__ tmv,
            const float* __restrict__ tmr,
            short* __restrict__ ka, short* __restrict__ va, short* __restrict__ ra)
{
    const size_t e = ((size_t)blockIdx.x * 256 + threadIdx.x) * 8;
    const size_t row = e >> 11;            // / Dd
    const int    col = (int)(e & (Dd - 1));
    const int    t   = (int)(row & (Tt - 1));

    const float* xp = x + e;
    float4 x0 = *(const float4*)xp, x1 = *(const float4*)(xp + 4);
    float4 s0 = make_float4(0,0,0,0), s1 = make_float4(0,0,0,0);
    if (t > 0) { s0 = *(const float4*)(xp - Dd); s1 = *(const float4*)(xp - Dd + 4); }

    float4 tk0 = *(const float4*)(tmk + col), tk1 = *(const float4*)(tmk + col + 4);
    float4 tv0 = *(const float4*)(tmv + col), tv1 = *(const float4*)(tmv + col + 4);
    float4 tr0 = *(const float4*)(tmr + col), tr1 = *(const float4*)(tmr + col + 4);

    float4 k0 = make_float4(mixf(x0.x,s0.x,tk0.x), mixf(x0.y,s0.y,tk0.y),
                            mixf(x0.z,s0.z,tk0.z), mixf(x0.w,s0.w,tk0.w));
    float4 k1 = make_float4(mixf(x1.x,s1.x,tk1.x), mixf(x1.y,s1.y,tk1.y),
                            mixf(x1.z,s1.z,tk1.z), mixf(x1.w,s1.w,tk1.w));
    float4 v0 = make_float4(mixf(x0.x,s0.x,tv0.x), mixf(x0.y,s0.y,tv0.y),
                            mixf(x0.z,s0.z,tv0.z), mixf(x0.w,s0.w,tv0.w));
    float4 v1 = make_float4(mixf(x1.x,s1.x,tv1.x), mixf(x1.y,s1.y,tv1.y),
                            mixf(x1.z,s1.z,tv1.z), mixf(x1.w,s1.w,tv1.w));
    float4 r0 = make_float4(siluf(mixf(x0.x,s0.x,tr0.x)), siluf(mixf(x0.y,s0.y,tr0.y)),
                            siluf(mixf(x0.z,s0.z,tr0.z)), siluf(mixf(x0.w,s0.w,tr0.w)));
    float4 r1 = make_float4(siluf(mixf(x1.x,s1.x,tr1.x)), siluf(mixf(x1.y,s1.y,tr1.y)),
                            siluf(mixf(x1.z,s1.z,tr1.z)), siluf(mixf(x1.w,s1.w,tr1.w)));

    *(short8*)(ka + e) = pack8(k0, k1);
    *(short8*)(va + e) = pack8(v0, v1);
    *(short8*)(ra + e) = pack8(r0, r1);
}

// ---- m97-style bf16 GEMM: C[m][n] = sum_k A[m][k]*B[n][k] + bias[n] ----
// A: M x K bf16 row-major, B: N x K bf16 row-major (nn.Linear W layout).
// 128x128 tile, BK=32, global_load_lds dwordx4, 2-barrier K-loop.
// OUTBF=1 -> bf16 out, OUTBF=0 -> fp32 out.
template<int OUTBF>
__global__ __launch_bounds__(256)
void gemm_bf16(const short* __restrict__ A, const short* __restrict__ B,
               const float* __restrict__ bias, void* __restrict__ Cout)
{
    __shared__ short As[128*32];   // 8 KB, unpadded (global_load_lds requires contiguity)
    __shared__ short Bs[128*32];   // 8 KB

    const int tid  = threadIdx.x;
    const int lane = tid & 63, wave = tid >> 6;
    const int row0 = blockIdx.x * 128;
    const int col0 = blockIdx.y * 128;

    // staging: lane l covers tile row srow=wave*32+(l>>2) (+16 for 2nd issue),
    // 16B chunk (l&3)*8 shorts. LDS rows are 64B so lane l lands at base+l*16. exact match.
    const int srow = wave * 32 + (lane >> 2);
    const int scol = (lane & 3) * 8;
    const short* Ag0 = A + (size_t)(row0 + srow) * Dd + scol;
    const short* Ag1 = Ag0 + (size_t)16 * Dd;
    const short* Bg0 = B + (size_t)(col0 + srow) * Dd + scol;
    const short* Bg1 = Bg0 + (size_t)16 * Dd;
    short* Al0 = As + (wave * 32     ) * 32;   // wave-uniform LDS bases
    short* Al1 = As + (wave * 32 + 16) * 32;
    short* Bl0 = Bs + (wave * 32     ) * 32;
    short* Bl1 = Bs + (wave * 32 + 16) * 32;

    const int wm = (wave >> 1) * 64, wn = (wave & 1) * 64;
    const int fm = lane & 15, fq = lane >> 4;

    floatx4 acc[4][4];
    #pragma unroll
    for (int i = 0; i < 4; i++)
        #pragma unroll
        for (int j = 0; j < 4; j++) acc[i][j] = (floatx4){0.f,0.f,0.f,0.f};

    for (int k0 = 0; k0 < Dd; k0 += 32) {
        __syncthreads();                       // prev iter's ds_reads done
        GLDS16(Ag0, Al0);
        GLDS16(Ag1, Al1);
        GLDS16(Bg0, Bl0);
        GLDS16(Bg1, Bl1);
        Ag0 += 32; Ag1 += 32; Bg0 += 32; Bg1 += 32;
        __syncthreads();                       // vmcnt(0) drain + barrier

        short8 af[4], bfv[4];
        #pragma unroll
        for (int i = 0; i < 4; i++)
            af[i] = *(const short8*)(As + (wm + i*16 + fm)*32 + fq*8);
        #pragma unroll
        for (int j = 0; j < 4; j++)
            bfv[j] = *(const short8*)(Bs + (wn + j*16 + fm)*32 + fq*8);
        #pragma unroll
        for (int i = 0; i < 4; i++)
            #pragma unroll
            for (int j = 0; j < 4; j++)
                acc[i][j] = __builtin_amdgcn_mfma_f32_16x16x32_bf16(af[i], bfv[j], acc[i][j], 0, 0, 0);
    }

    // epilogue: C/D layout col=lane&15, row=(lane>>4)*4+r
    #pragma unroll
    for (int j = 0; j < 4; j++) {
        const int gc = col0 + wn + j*16 + fm;
        const float bj = bias[gc];
        #pragma unroll
        for (int i = 0; i < 4; i++) {
            const int gr = row0 + wm + i*16 + fq*4;
            #pragma unroll
            for (int r = 0; r < 4; r++) {
                const float v = acc[i][j][r] + bj;
                if constexpr (OUTBF)
                    ((short*)Cout)[(size_t)(gr + r) * Dd + gc] = f2bf(v);
                else
                    ((float*)Cout)[(size_t)(gr + r) * Dd + gc] = v;
            }
        }
    }
}

// ---------------- chunked WKV scan (K/V/R now bf16) ----------------
__global__ __launch_bounds__(256)
void scan1(const short* __restrict__ K, const short* __restrict__ V,
           const float* __restrict__ u, const float* __restrict__ w,
           float* __restrict__ Asum, float* __restrict__ Bsum, float* __restrict__ Dsum)
{
    const int c = blockIdx.x, b = blockIdx.y;
    const int d = blockIdx.z * 256 + threadIdx.x;
    const float uu = u[d], ww = w[d];
    const size_t base = ((size_t)(b*Tt + c*CHUNK)) * Dd + d;
    float a = 0.f, bb = 0.f, dd = 1.f;
    #pragma unroll 4
    for (int t = 0; t < CHUNK; t++) {
        const float k = bf2f(K[base + (size_t)t*Dd]);
        const float v = bf2f(V[base + (size_t)t*Dd]);
        const float tt = fmaxf(uu + k, ww);
        const float e1 = __expf(-ww - tt);
        const float e2 = __expf(uu + k - tt);
        a  = e1*a  + e2*v;
        bb = e1*bb + e2;
        dd *= e1;
    }
    const size_t idx = ((size_t)c*Bb + b) * Dd + d;
    Asum[idx] = a; Bsum[idx] = bb; Dsum[idx] = dd;
}

__global__ __launch_bounds__(256)
void scan2(const float* __restrict__ Asum, const float* __restrict__ Bsum,
           const float* __restrict__ Dsum, float* __restrict__ Sa, float* __restrict__ Sb)
{
    const int g = blockIdx.x * 256 + threadIdx.x;   // (b,d) channel: 0..8191
    float a = 0.f, bb = 0.f;
    for (int c = 0; c < NCHUNK; c++) {
        const size_t idx = (size_t)c * (Bb*Dd) + g;
        Sa[idx] = a; Sb[idx] = bb;
        const float dd = Dsum[idx];
        a  = dd*a  + Asum[idx];
        bb = dd*bb + Bsum[idx];
    }
}

__global__ __launch_bounds__(256)
void scan3(const short* __restrict__ K, const short* __restrict__ V,
           const short* __restrict__ R,
           const float* __restrict__ Sa, const float* __restrict__ Sb,
           const float* __restrict__ u, const float* __restrict__ w,
           short* __restrict__ AF)
{
    const int c = blockIdx.x, b = blockIdx.y;
    const int d = blockIdx.z * 256 + threadIdx.x;
    const float uu = u[d], ww = w[d];
    const size_t sidx = ((size_t)c*Bb + b) * Dd + d;
    float a = Sa[sidx], bb = Sb[sidx];
    const size_t base = ((size_t)(b*Tt + c*CHUNK)) * Dd + d;
    #pragma unroll 4
    for (int t = 0; t < CHUNK; t++) {
        const float k = bf2f(K[base + (size_t)t*Dd]);
        const float v = bf2f(V[base + (size_t)t*Dd]);
        const float tt = fmaxf(uu + k, ww);
        const float e1 = __expf(-ww - tt);
        const float e2 = __expf(uu + k - tt);
        a  = e1*a  + e2*v;
        bb = e1*bb + e2;
        const float wkv = a / bb;
        const float r = bf2f(R[base + (size_t)t*Dd]);
        AF[base + (size_t)t*Dd] = f2bf(wkv * r);
    }
}

extern "C" void kernel_launch(void* const* d_in, const int* in_sizes, int n_in,
                              void* d_out, int out_size, void* d_ws, size_t ws_size,
                              hipStream_t stream)
{
    const float* x   = (const float*)d_in[0];
    const float* Wk  = (const float*)d_in[1];
    const float* bk  = (const float*)d_in[2];
    const float* Wv  = (const float*)d_in[3];
    const float* bv  = (const float*)d_in[4];
    const float* Wr  = (const float*)d_in[5];
    const float* br  = (const float*)d_in[6];
    const float* Wo  = (const float*)d_in[7];
    const float* bo  = (const float*)d_in[8];
    const float* tmk = (const float*)d_in[9];
    const float* tmv = (const float*)d_in[10];
    const float* tmr = (const float*)d_in[11];
    const float* u   = (const float*)d_in[12];
    const float* w   = (const float*)d_in[13];

    char* ws = (char*)d_ws;
    short* Wkb  = (short*)(ws + 0x00000000ull);   // 8 MB each
    short* Wvb  = (short*)(ws + 0x00800000ull);
    short* Wrb  = (short*)(ws + 0x01000000ull);
    short* Wob  = (short*)(ws + 0x01800000ull);
    short* ka   = (short*)(ws + 0x02000000ull);   // 64 MB each (M x D bf16)
    short* va   = (short*)(ws + 0x06000000ull);
    short* ra   = (short*)(ws + 0x0A000000ull);
    short* Kb   = (short*)(ws + 0x0E000000ull);
    short* Vb   = (short*)(ws + 0x12000000ull);
    short* Rb   = (short*)(ws + 0x16000000ull);
    float* Asum = (float*)(ws + 0x1A000000ull);   // 2 MB each
    float* Bsum = (float*)(ws + 0x1A200000ull);
    float* Dsum = (float*)(ws + 0x1A400000ull);
    float* Sa   = (float*)(ws + 0x1A600000ull);
    float* Sb   = (float*)(ws + 0x1A800000ull);
    short* AF   = ka;   // ka is dead after the K-projection GEMM; reuse for wkv*r

    prep_w<<<dim3(2048, 4), 256, 0, stream>>>(Wk, Wv, Wr, Wo, Wkb, Wvb, Wrb, Wob);
    prep_a<<<dim3(16384), 256, 0, stream>>>(x, tmk, tmv, tmr, ka, va, ra);

    dim3 gg(Mm/128, Dd/128);   // 128 x 16
    gemm_bf16<1><<<gg, 256, 0, stream>>>(ka, Wkb, bk, Kb);
    gemm_bf16<1><<<gg, 256, 0, stream>>>(va, Wvb, bv, Vb);
    gemm_bf16<1><<<gg, 256, 0, stream>>>(ra, Wrb, br, Rb);

    scan1<<<dim3(NCHUNK, Bb, Dd/256), 256, 0, stream>>>(Kb, Vb, u, w, Asum, Bsum, Dsum);
    scan2<<<dim3((Bb*Dd)/256), 256, 0, stream>>>(Asum, Bsum, Dsum, Sa, Sb);
    scan3<<<dim3(NCHUNK, Bb, Dd/256), 256, 0, stream>>>(Kb, Vb, Rb, Sa, Sb, u, w, AF);

    gemm_bf16<0><<<gg, 256, 0, stream>>>(AF, Wob, bo, (float*)d_out);
}